// Round 4
// baseline (83.653 us; speedup 1.0000x reference)
//
#include <hip/hip_runtime.h>
#include <hip/hip_bf16.h>

// GridEmbedding: out[tok, h] = emb_table[input_ids[tok], h]
//                + grid_mask[tok] * ((row_idx[tok]+1)*row_vec[h] + (col_idx[tok]+1)*col_vec[h])
// B*S = 32768 tokens, H = 2048, float32. Memory-bound gather + broadcast FMA.
//
// Mapping: one 64-lane wave per 2 tokens -> 16 independent float4 row-loads in
// flight per lane before any store (deeper MLP than 1-token/wave). 4 waves per
// 256-thread block -> 8 tokens/block -> 4096 blocks. Output is write-once:
// nontemporal stores keep L2/L3 free so duplicate emb rows stay cached.

#define HIDDEN 2048
#define NTOK (4 * 8192)

typedef float vfloat4 __attribute__((ext_vector_type(4)));

__global__ __launch_bounds__(256) void GridEmbedding_64046552318105_kernel(
    const int* __restrict__ ids,
    const int* __restrict__ rows,
    const int* __restrict__ cols,
    const int* __restrict__ mask,
    const float* __restrict__ emb,
    const float* __restrict__ rvec,
    const float* __restrict__ cvec,
    float* __restrict__ out) {
    const int wave = threadIdx.x >> 6;               // 0..3
    const int lane = threadIdx.x & 63;               // 0..63
    const int tok0 = blockIdx.x * 8 + wave * 2;      // two tokens per wave
    const int tok1 = tok0 + 1;

    const long long id0 = (long long)ids[tok0];
    const long long id1 = (long long)ids[tok1];
    const float r0 = (float)(rows[tok0] + 1);
    const float r1 = (float)(rows[tok1] + 1);
    const float c0 = (float)(cols[tok0] + 1);
    const float c1 = (float)(cols[tok1] + 1);
    const bool m0 = mask[tok0] != 0;
    const bool m1 = mask[tok1] != 0;

    const vfloat4* __restrict__ src0 = reinterpret_cast<const vfloat4*>(emb + id0 * HIDDEN);
    const vfloat4* __restrict__ src1 = reinterpret_cast<const vfloat4*>(emb + id1 * HIDDEN);
    const vfloat4* __restrict__ rv   = reinterpret_cast<const vfloat4*>(rvec);
    const vfloat4* __restrict__ cv   = reinterpret_cast<const vfloat4*>(cvec);
    vfloat4* __restrict__ dst0 = reinterpret_cast<vfloat4*>(out + (long long)tok0 * HIDDEN);
    vfloat4* __restrict__ dst1 = reinterpret_cast<vfloat4*>(out + (long long)tok1 * HIDDEN);

    // 512 float4 per token; 64 lanes -> 8 float4/lane/token. Issue all 16
    // independent loads before any dependent work.
    vfloat4 e0[8], e1[8];
    #pragma unroll
    for (int i = 0; i < 8; ++i) e0[i] = src0[lane + i * 64];
    #pragma unroll
    for (int i = 0; i < 8; ++i) e1[i] = src1[lane + i * 64];

    if (m0) {
        #pragma unroll
        for (int i = 0; i < 8; ++i) {
            const int j = lane + i * 64;
            e0[i] += r0 * rv[j] + c0 * cv[j];
        }
    }
    #pragma unroll
    for (int i = 0; i < 8; ++i)
        __builtin_nontemporal_store(e0[i], &dst0[lane + i * 64]);

    if (m1) {
        #pragma unroll
        for (int i = 0; i < 8; ++i) {
            const int j = lane + i * 64;
            e1[i] += r1 * rv[j] + c1 * cv[j];
        }
    }
    #pragma unroll
    for (int i = 0; i < 8; ++i)
        __builtin_nontemporal_store(e1[i], &dst1[lane + i * 64]);
}

extern "C" void kernel_launch(void* const* d_in, const int* in_sizes, int n_in,
                              void* d_out, int out_size, void* d_ws, size_t ws_size,
                              hipStream_t stream) {
    const int*   ids  = (const int*)d_in[0];
    const int*   rows = (const int*)d_in[1];
    const int*   cols = (const int*)d_in[2];
    const int*   mask = (const int*)d_in[3];
    const float* emb  = (const float*)d_in[4];
    const float* rvec = (const float*)d_in[5];
    const float* cvec = (const float*)d_in[6];
    float* out = (float*)d_out;

    GridEmbedding_64046552318105_kernel<<<NTOK / 8, 256, 0, stream>>>(
        ids, rows, cols, mask, emb, rvec, cvec, out);
}

// Round 5
// 82.631 us; speedup vs baseline: 1.0124x; 1.0124x over previous
//
#include <hip/hip_runtime.h>
#include <hip/hip_bf16.h>

// GridEmbedding: out[tok, h] = emb_table[input_ids[tok], h]
//                + grid_mask[tok] * ((row_idx[tok]+1)*row_vec[h] + (col_idx[tok]+1)*col_vec[h])
// B*S = 32768 tokens, H = 2048, float32. Memory-bound gather + broadcast FMA.
//
// Best measured config (R3, 82.5 us): one 64-lane wave per token (8 independent
// float4 loads/lane), 4 waves per 256-thread block -> 8192 blocks. Nontemporal
// stores keep the 268 MB write-once output out of L2/L3 so duplicate emb rows
// (~26% of tokens) stay L3-resident. R4 showed 2 tokens/wave is NOT better
// (83.65 us) -> bandwidth-saturated, not latency-limited.
// All offsets fit int32 (50257*2048 < 2^31): 32-bit index math only.

#define HIDDEN 2048
#define NTOK (4 * 8192)

typedef float vfloat4 __attribute__((ext_vector_type(4)));

__global__ __launch_bounds__(256) void GridEmbedding_64046552318105_kernel(
    const int* __restrict__ ids,
    const int* __restrict__ rows,
    const int* __restrict__ cols,
    const int* __restrict__ mask,
    const float* __restrict__ emb,
    const float* __restrict__ rvec,
    const float* __restrict__ cvec,
    float* __restrict__ out) {
    const int wave = threadIdx.x >> 6;              // 0..3
    const int lane = threadIdx.x & 63;              // 0..63
    const int tok  = (blockIdx.x << 2) + wave;      // one wave per token

    const int id = ids[tok];                        // wave-uniform -> scalar loads
    const float r = (float)(rows[tok] + 1);
    const float c = (float)(cols[tok] + 1);
    const bool m = mask[tok] != 0;

    // 32-bit element offsets (max 50257*512 float4 < 2^31)
    const vfloat4* __restrict__ src = reinterpret_cast<const vfloat4*>(emb) + id * 512;
    const vfloat4* __restrict__ rv  = reinterpret_cast<const vfloat4*>(rvec);
    const vfloat4* __restrict__ cv  = reinterpret_cast<const vfloat4*>(cvec);
    vfloat4* __restrict__ dst = reinterpret_cast<vfloat4*>(out) + tok * 512;

    // 512 float4 per token; 64 lanes -> 8 independent float4/lane.
    vfloat4 e[8];
    #pragma unroll
    for (int i = 0; i < 8; ++i) e[i] = src[lane + i * 64];

    if (m) {
        #pragma unroll
        for (int i = 0; i < 8; ++i) {
            const int j = lane + i * 64;
            e[i] += r * rv[j] + c * cv[j];
        }
    }

    #pragma unroll
    for (int i = 0; i < 8; ++i)
        __builtin_nontemporal_store(e[i], &dst[lane + i * 64]);
}

extern "C" void kernel_launch(void* const* d_in, const int* in_sizes, int n_in,
                              void* d_out, int out_size, void* d_ws, size_t ws_size,
                              hipStream_t stream) {
    const int*   ids  = (const int*)d_in[0];
    const int*   rows = (const int*)d_in[1];
    const int*   cols = (const int*)d_in[2];
    const int*   mask = (const int*)d_in[3];
    const float* emb  = (const float*)d_in[4];
    const float* rvec = (const float*)d_in[5];
    const float* cvec = (const float*)d_in[6];
    float* out = (float*)d_out;

    GridEmbedding_64046552318105_kernel<<<NTOK / 4, 256, 0, stream>>>(
        ids, rows, cols, mask, emb, rvec, cvec, out);
}